// Round 3
// baseline (517.265 us; speedup 1.0000x reference)
//
#include <hip/hip_runtime.h>

#define SS 2048
#define DD 64

typedef unsigned short ushort_t;
typedef __attribute__((ext_vector_type(4)))  float f32x4;
typedef __attribute__((ext_vector_type(16))) float f32x16;
typedef __attribute__((ext_vector_type(8)))  short bf16x8;
typedef __attribute__((ext_vector_type(2)))  unsigned int u32x2;

static __device__ __forceinline__ unsigned short f2bf(float f) {
    unsigned u = __builtin_bit_cast(unsigned, f);
    u += 0x7FFFu + ((u >> 16) & 1u);
    return (unsigned short)(u >> 16);
}

static __device__ __forceinline__ f32x16 zero16() {
    f32x16 z;
#pragma unroll
    for (int i = 0; i < 16; ++i) z[i] = 0.f;
    return z;
}

union PFrag { bf16x8 v; unsigned w[4]; };

// ---------------- prologue: fp32 -> bf16 ----------------
__global__ void cvt_bf16(const float* __restrict__ src, ushort_t* __restrict__ dst,
                         int n8, float scale)
{
    int i = blockIdx.x * blockDim.x + threadIdx.x;
    if (i >= n8) return;
    f32x4 a = ((const f32x4*)src)[2 * i];
    f32x4 b = ((const f32x4*)src)[2 * i + 1];
    bf16x8 o;
#pragma unroll
    for (int j = 0; j < 4; ++j) o[j] = (short)f2bf(a[j] * scale);
#pragma unroll
    for (int j = 0; j < 4; ++j) o[4 + j] = (short)f2bf(b[j] * scale);
    ((bf16x8*)dst)[i] = o;
}

// ---------------- prologue: V [h][kv][d] fp32 -> V^T [h][d][kv] bf16 ----------------
__global__ void transposeV(const float* __restrict__ V, ushort_t* __restrict__ Vt)
{
    __shared__ float tile[64][65];
    const int tid = threadIdx.x;
    const int hh = blockIdx.x >> 5;
    const int kt = blockIdx.x & 31;

#pragma unroll
    for (int it = 0; it < 4; ++it) {
        int m = it * 256 + tid;
        int r = m >> 4, c4 = m & 15;
        f32x4 v = *(const f32x4*)(V + ((size_t)(hh * SS + kt * 64 + r)) * DD + c4 * 4);
#pragma unroll
        for (int j = 0; j < 4; ++j) tile[r][c4 * 4 + j] = v[j];
    }
    __syncthreads();
#pragma unroll
    for (int it = 0; it < 2; ++it) {
        int m = it * 256 + tid;
        int d = m >> 3, c8 = m & 7;
        bf16x8 o;
#pragma unroll
        for (int j = 0; j < 8; ++j) o[j] = (short)f2bf(tile[c8 * 8 + j][d]);
        *(bf16x8*)(Vt + ((size_t)hh * DD + d) * SS + kt * 64 + c8 * 8) = o;
    }
}

// ---------------- main: barrier-free K/V-from-L2, kv-split across 4 waves ----------------
__global__ __launch_bounds__(256, 3)
void attn_main2(const float* __restrict__ gQ, const ushort_t* __restrict__ Kbf,
                const ushort_t* __restrict__ Vtbf, float* __restrict__ gO,
                float* __restrict__ gP)
{
    __shared__ float lsm[4 * 32];          // per-wave partial denominators
    __shared__ float osm[4 * 64 * 33];     // per-wave partial O^T [w][d][q], padded

    const int tid  = threadIdx.x;
    const int lane = tid & 63;
    const int wave = tid >> 6;
    const int lo5  = lane & 31;
    const int hi   = lane >> 5;

    const int bid  = blockIdx.x;
    const int wg   = (bid & 7) * 256 + (bid >> 3);   // XCD-contiguous: 4 heads per XCD
    const int head = wg >> 6;
    const int q0b  = (wg & 63) * 32;

    const float*    Qh = gQ   + (size_t)head * SS * DD;
    const ushort_t* Kh = Kbf  + (size_t)head * SS * DD;
    const ushort_t* Vh = Vtbf + (size_t)head * DD * SS;   // [d][kv]
    float* Oh = gO + (size_t)head * SS * DD;
    float* Ph = gP + (size_t)head * SS * SS;

    const float SCALE = 0.125f * 1.44269504088896340736f; // (1/sqrt(64)) * log2(e)

    // ---- Q B-fragments from fp32 global, scale folded ----
    const int qrow = q0b + lo5;
    bf16x8 qf[4];
#pragma unroll
    for (int ks = 0; ks < 4; ++ks) {
        const float* qp = Qh + (size_t)qrow * DD + ks * 16 + hi * 8;
        f32x4 a = *(const f32x4*)(qp);
        f32x4 b = *(const f32x4*)(qp + 4);
        bf16x8 o;
#pragma unroll
        for (int j = 0; j < 4; ++j) o[j] = (short)f2bf(a[j] * SCALE);
#pragma unroll
        for (int j = 0; j < 4; ++j) o[4 + j] = (short)f2bf(b[j] * SCALE);
        qf[ks] = o;
    }

    const int kv_base = wave * 512;        // this wave's kv range [kv_base, kv_base+512)

    // ================= PASS A: denominator (max-free) =================
    float ls0 = 0.f, ls1 = 0.f;
#pragma unroll 2
    for (int t = 0; t < 8; ++t) {
        int kv0 = kv_base + t * 64;
#pragma unroll
        for (int sub = 0; sub < 2; ++sub) {
            f32x16 acc = zero16();
            const ushort_t* kp = Kh + (size_t)(kv0 + sub * 32 + lo5) * DD + hi * 8;
#pragma unroll
            for (int ks = 0; ks < 4; ++ks) {
                bf16x8 kf = *(const bf16x8*)(kp + ks * 16);
                acc = __builtin_amdgcn_mfma_f32_32x32x16_bf16(kf, qf[ks], acc, 0, 0, 0);
            }
#pragma unroll
            for (int r = 0; r < 16; r += 2) {
                ls0 += __builtin_exp2f(acc[r]);
                ls1 += __builtin_exp2f(acc[r + 1]);
            }
        }
    }
    float lsum = ls0 + ls1;
    lsum += __shfl_xor(lsum, 32);
    lsm[wave * 32 + lo5] = lsum;           // both halves write same value
    __syncthreads();
    const float rinv = 1.0f / (lsm[lo5] + lsm[32 + lo5] + lsm[64 + lo5] + lsm[96 + lo5]);

    // ================= PASS B: scores, P write, PV =================
    f32x16 o0 = zero16(), o1 = zero16();
    float* prow_base = Ph + (size_t)qrow * SS;

#pragma unroll 2
    for (int t = 0; t < 8; ++t) {
        int kv0 = kv_base + t * 64;
#pragma unroll
        for (int sub = 0; sub < 2; ++sub) {
            f32x16 acc = zero16();
            const ushort_t* kp = Kh + (size_t)(kv0 + sub * 32 + lo5) * DD + hi * 8;
#pragma unroll
            for (int ks = 0; ks < 4; ++ks) {
                bf16x8 kf = *(const bf16x8*)(kp + ks * 16);
                acc = __builtin_amdgcn_mfma_f32_32x32x16_bf16(kf, qf[ks], acc, 0, 0, 0);
            }
            float pr[16];
#pragma unroll
            for (int r = 0; r < 16; ++r) pr[r] = __builtin_exp2f(acc[r]);

            // store normalized P (nontemporal: don't thrash L2 holding K/V^T)
            float* prow = prow_base + kv0 + sub * 32;
#pragma unroll
            for (int g = 0; g < 4; ++g) {
                f32x4 st = { pr[4*g+0] * rinv, pr[4*g+1] * rinv, pr[4*g+2] * rinv, pr[4*g+3] * rinv };
                __builtin_nontemporal_store(st, (f32x4*)(prow + g * 8 + hi * 4));
            }

            // pack unnormalized p to bf16 pairs
            unsigned u[8];
#pragma unroll
            for (int j = 0; j < 8; ++j)
                u[j] = (unsigned)f2bf(pr[2*j]) | ((unsigned)f2bf(pr[2*j+1]) << 16);

            // assemble P^T B-frags via half-wave exchange
            unsigned s0 = __shfl_xor(u[0], 32), s1 = __shfl_xor(u[1], 32);
            unsigned s2 = __shfl_xor(u[2], 32), s3 = __shfl_xor(u[3], 32);
            unsigned s4 = __shfl_xor(u[4], 32), s5 = __shfl_xor(u[5], 32);
            unsigned s6 = __shfl_xor(u[6], 32), s7 = __shfl_xor(u[7], 32);
            PFrag pf0, pf1;
            pf0.w[0] = hi ? s2 : u[0];  pf0.w[1] = hi ? s3 : u[1];
            pf0.w[2] = hi ? u[2] : s0;  pf0.w[3] = hi ? u[3] : s1;
            pf1.w[0] = hi ? s6 : u[4];  pf1.w[1] = hi ? s7 : u[5];
            pf1.w[2] = hi ? u[6] : s4;  pf1.w[3] = hi ? u[7] : s5;

            // PV: O^T[64d][32q] += V^T * P^T, V^T frags straight from L2
#pragma unroll
            for (int dt = 0; dt < 2; ++dt) {
                const ushort_t* vp = Vh + (size_t)(dt * 32 + lo5) * SS + kv0 + sub * 32 + hi * 8;
                bf16x8 vf0 = *(const bf16x8*)(vp);
                bf16x8 vf1 = *(const bf16x8*)(vp + 16);
                f32x16& od = dt ? o1 : o0;
                od = __builtin_amdgcn_mfma_f32_32x32x16_bf16(vf0, pf0.v, od, 0, 0, 0);
                od = __builtin_amdgcn_mfma_f32_32x32x16_bf16(vf1, pf1.v, od, 0, 0, 0);
            }
        }
    }

    // ---- write per-wave O^T partials to LDS: reg 4g+j of tile dt is d = dt*32+8g+4hi+j ----
#pragma unroll
    for (int dt = 0; dt < 2; ++dt) {
        const f32x16& od = dt ? o1 : o0;
#pragma unroll
        for (int g = 0; g < 4; ++g) {
#pragma unroll
            for (int j = 0; j < 4; ++j) {
                int d = dt * 32 + g * 8 + hi * 4 + j;
                osm[(wave * 64 + d) * 33 + lo5] = od[4 * g + j];
            }
        }
    }
    __syncthreads();

    // ---- reduce 4 wave partials, normalize, store O ----
    {
        const int q  = tid >> 3;
        const int d0 = (tid & 7) * 8;
        const float rq = 1.0f / (lsm[q] + lsm[32 + q] + lsm[64 + q] + lsm[96 + q]);
        float out[8];
#pragma unroll
        for (int i = 0; i < 8; ++i) {
            int d = d0 + i;
            out[i] = (osm[(0 * 64 + d) * 33 + q] + osm[(1 * 64 + d) * 33 + q] +
                      osm[(2 * 64 + d) * 33 + q] + osm[(3 * 64 + d) * 33 + q]) * rq;
        }
        float* op = Oh + (size_t)(q0b + q) * DD + d0;
        f32x4 a = { out[0], out[1], out[2], out[3] };
        f32x4 b = { out[4], out[5], out[6], out[7] };
        *(f32x4*)(op)     = a;
        *(f32x4*)(op + 4) = b;
    }
}

// ================= fallback (no-ws path) =================
__global__ __launch_bounds__(256, 2)
void attn_fused(const float* __restrict__ gQ, const float* __restrict__ gK,
                const float* __restrict__ gV, float* __restrict__ gO,
                float* __restrict__ gP)
{
    __shared__ unsigned short Qs[128 * DD];
    __shared__ unsigned short Ks[64 * DD];
    __shared__ unsigned short Vt[DD * 64];

    const int tid  = threadIdx.x;
    const int lane = tid & 63;
    const int wave = tid >> 6;
    const int lo5  = lane & 31;
    const int hi   = lane >> 5;

    const int head = blockIdx.x >> 4;
    const int q0b  = (blockIdx.x & 15) * 128;

    const float* Qh = gQ + (size_t)head * SS * DD;
    const float* Kh = gK + (size_t)head * SS * DD;
    const float* Vh = gV + (size_t)head * SS * DD;
    float* Oh = gO + (size_t)head * SS * DD;
    float* Ph = gP + (size_t)head * SS * SS;

    const float SCALE = 0.125f * 1.44269504088896340736f;

#pragma unroll
    for (int it = 0; it < 8; ++it) {
        int m = it * 256 + tid;
        int q = m >> 4, d4 = m & 15;
        f32x4 v = *(const f32x4*)(Qh + (size_t)(q0b + q) * DD + d4 * 4);
        unsigned a = (unsigned)f2bf(v.x * SCALE) | ((unsigned)f2bf(v.y * SCALE) << 16);
        unsigned b = (unsigned)f2bf(v.z * SCALE) | ((unsigned)f2bf(v.w * SCALE) << 16);
        u32x2 w; w.x = a; w.y = b;
        *(u32x2*)(Qs + q * 64 + d4 * 4) = w;
    }
    __syncthreads();

    const int qrow = wave * 32 + lo5;
    bf16x8 qf[4];
#pragma unroll
    for (int ks = 0; ks < 4; ++ks)
        qf[ks] = *(const bf16x8*)(Qs + qrow * 64 + ks * 16 + hi * 8);

    auto stageK = [&](int kv0) {
#pragma unroll
        for (int it = 0; it < 4; ++it) {
            int m = it * 256 + tid;
            int kv = m >> 4, d4 = m & 15;
            f32x4 v = *(const f32x4*)(Kh + (size_t)(kv0 + kv) * DD + d4 * 4);
            unsigned a = (unsigned)f2bf(v.x) | ((unsigned)f2bf(v.y) << 16);
            unsigned b = (unsigned)f2bf(v.z) | ((unsigned)f2bf(v.w) << 16);
            int c16 = (d4 >> 1) ^ (kv & 7);
            u32x2 w; w.x = a; w.y = b;
            *(u32x2*)(Ks + kv * 64 + c16 * 8 + (d4 & 1) * 4) = w;
        }
    };
    auto stageV = [&](int kv0) {
#pragma unroll
        for (int it = 0; it < 2; ++it) {
            int m = it * 256 + tid;
            int kv2 = m >> 4, d4 = m & 15;
            const float* p0 = Vh + (size_t)(kv0 + kv2 * 2) * DD + d4 * 4;
            f32x4 v0 = *(const f32x4*)(p0);
            f32x4 v1 = *(const f32x4*)(p0 + DD);
#pragma unroll
            for (int c = 0; c < 4; ++c) {
                int d = d4 * 4 + c;
                unsigned u = (unsigned)f2bf(v0[c]) | ((unsigned)f2bf(v1[c]) << 16);
                int c16 = (kv2 >> 2) ^ (d & 7);
                *(unsigned*)(Vt + d * 64 + c16 * 8 + (kv2 & 3) * 2) = u;
            }
        }
    };

    float m_run = -1e30f, l_run = 0.f;
    for (int kv0 = 0; kv0 < SS; kv0 += 64) {
        __syncthreads();
        stageK(kv0);
        __syncthreads();
#pragma unroll
        for (int sub = 0; sub < 2; ++sub) {
            f32x16 acc = zero16();
            int kvl = sub * 32 + lo5;
#pragma unroll
            for (int ks = 0; ks < 4; ++ks) {
                bf16x8 kf = *(const bf16x8*)(Ks + kvl * 64 + ((((ks * 2) + hi) ^ (kvl & 7)) << 3));
                acc = __builtin_amdgcn_mfma_f32_32x32x16_bf16(kf, qf[ks], acc, 0, 0, 0);
            }
            float tm = acc[0];
#pragma unroll
            for (int r = 1; r < 16; ++r) tm = fmaxf(tm, acc[r]);
            float mn = fmaxf(m_run, tm);
            float sum = 0.f;
#pragma unroll
            for (int r = 0; r < 16; ++r) sum += __builtin_exp2f(acc[r] - mn);
            l_run = l_run * __builtin_exp2f(m_run - mn) + sum;
            m_run = mn;
        }
    }
    {
        float mo = __shfl_xor(m_run, 32);
        float mf = fmaxf(m_run, mo);
        float la = l_run * __builtin_exp2f(m_run - mf);
        float lb = __shfl_xor(la, 32);
        l_run = la + lb;
        m_run = mf;
    }
    const float rinv = 1.0f / l_run;

    f32x16 o0 = zero16(), o1 = zero16();
    const int qg = q0b + wave * 32 + lo5;
    float* prow_base = Ph + (size_t)qg * SS;

    for (int kv0 = 0; kv0 < SS; kv0 += 64) {
        __syncthreads();
        stageK(kv0);
        stageV(kv0);
        __syncthreads();
#pragma unroll
        for (int sub = 0; sub < 2; ++sub) {
            f32x16 acc = zero16();
            int kvl = sub * 32 + lo5;
#pragma unroll
            for (int ks = 0; ks < 4; ++ks) {
                bf16x8 kf = *(const bf16x8*)(Ks + kvl * 64 + ((((ks * 2) + hi) ^ (kvl & 7)) << 3));
                acc = __builtin_amdgcn_mfma_f32_32x32x16_bf16(kf, qf[ks], acc, 0, 0, 0);
            }
            float pr[16];
#pragma unroll
            for (int r = 0; r < 16; ++r) pr[r] = __builtin_exp2f(acc[r] - m_run);

            float* prow = prow_base + kv0 + sub * 32;
#pragma unroll
            for (int g = 0; g < 4; ++g) {
                f32x4 st = { pr[4*g+0] * rinv, pr[4*g+1] * rinv, pr[4*g+2] * rinv, pr[4*g+3] * rinv };
                *(f32x4*)(prow + g * 8 + hi * 4) = st;
            }

            unsigned u[8];
#pragma unroll
            for (int j = 0; j < 8; ++j)
                u[j] = (unsigned)f2bf(pr[2*j]) | ((unsigned)f2bf(pr[2*j+1]) << 16);

            unsigned s0 = __shfl_xor(u[0], 32), s1 = __shfl_xor(u[1], 32);
            unsigned s2 = __shfl_xor(u[2], 32), s3 = __shfl_xor(u[3], 32);
            unsigned s4 = __shfl_xor(u[4], 32), s5 = __shfl_xor(u[5], 32);
            unsigned s6 = __shfl_xor(u[6], 32), s7 = __shfl_xor(u[7], 32);
            PFrag pf0, pf1;
            pf0.w[0] = hi ? s2 : u[0];  pf0.w[1] = hi ? s3 : u[1];
            pf0.w[2] = hi ? u[2] : s0;  pf0.w[3] = hi ? u[3] : s1;
            pf1.w[0] = hi ? s6 : u[4];  pf1.w[1] = hi ? s7 : u[5];
            pf1.w[2] = hi ? u[6] : s4;  pf1.w[3] = hi ? u[7] : s5;

#pragma unroll
            for (int dt = 0; dt < 2; ++dt) {
                int drow = dt * 32 + lo5;
                int c0 = ((sub * 4) + 0 + hi) ^ (drow & 7);
                int c1 = ((sub * 4) + 2 + hi) ^ (drow & 7);
                bf16x8 vf0 = *(const bf16x8*)(Vt + drow * 64 + (c0 << 3));
                bf16x8 vf1 = *(const bf16x8*)(Vt + drow * 64 + (c1 << 3));
                f32x16& od = dt ? o1 : o0;
                od = __builtin_amdgcn_mfma_f32_32x32x16_bf16(vf0, pf0.v, od, 0, 0, 0);
                od = __builtin_amdgcn_mfma_f32_32x32x16_bf16(vf1, pf1.v, od, 0, 0, 0);
            }
        }
    }

    float* orow = Oh + (size_t)qg * DD;
#pragma unroll
    for (int dt = 0; dt < 2; ++dt) {
        const f32x16& od = dt ? o1 : o0;
#pragma unroll
        for (int g = 0; g < 4; ++g) {
            f32x4 st = { od[4*g+0] * rinv, od[4*g+1] * rinv, od[4*g+2] * rinv, od[4*g+3] * rinv };
            *(f32x4*)(orow + dt * 32 + g * 8 + hi * 4) = st;
        }
    }
}

extern "C" void kernel_launch(void* const* d_in, const int* in_sizes, int n_in,
                              void* d_out, int out_size, void* d_ws, size_t ws_size,
                              hipStream_t stream) {
    const float* Q = (const float*)d_in[0];
    const float* K = (const float*)d_in[1];
    const float* V = (const float*)d_in[2];
    float* O = (float*)d_out;
    float* P = O + (size_t)2 * 16 * SS * DD;

    const size_t HD = (size_t)32 * SS * DD;           // elems per tensor
    const size_t need = 2 * HD * sizeof(ushort_t);    // K bf16 + V^T bf16 ≈ 16.8 MB

    if (ws_size >= need) {
        ushort_t* Kbf  = (ushort_t*)d_ws;
        ushort_t* Vtbf = Kbf + HD;
        int n8 = (int)(HD / 8);
        hipLaunchKernelGGL(cvt_bf16, dim3(n8 / 256), dim3(256), 0, stream, K, Kbf, n8, 1.0f);
        hipLaunchKernelGGL(transposeV, dim3(1024), dim3(256), 0, stream, V, Vtbf);
        hipLaunchKernelGGL(attn_main2, dim3(2048), dim3(256), 0, stream, Q, Kbf, Vtbf, O, P);
    } else {
        hipLaunchKernelGGL(attn_fused, dim3(512), dim3(256), 0, stream, Q, K, V, O, P);
    }
}

// Round 4
// 276.080 us; speedup vs baseline: 1.8736x; 1.8736x over previous
//
#include <hip/hip_runtime.h>

#define SS 2048
#define DD 64

typedef unsigned short ushort_t;
typedef __attribute__((ext_vector_type(4)))  float f32x4;
typedef __attribute__((ext_vector_type(16))) float f32x16;
typedef __attribute__((ext_vector_type(8)))  short bf16x8;
typedef __attribute__((ext_vector_type(2)))  unsigned int u32x2;

static __device__ __forceinline__ unsigned short f2bf(float f) {
    unsigned u = __builtin_bit_cast(unsigned, f);
    u += 0x7FFFu + ((u >> 16) & 1u);
    return (unsigned short)(u >> 16);
}

static __device__ __forceinline__ f32x16 zero16() {
    f32x16 z;
#pragma unroll
    for (int i = 0; i < 16; ++i) z[i] = 0.f;
    return z;
}

union PFrag { bf16x8 v; unsigned w[4]; };

// ---------------- prologue: fp32 -> bf16 ----------------
__global__ void cvt_bf16(const float* __restrict__ src, ushort_t* __restrict__ dst,
                         int n8, float scale)
{
    int i = blockIdx.x * blockDim.x + threadIdx.x;
    if (i >= n8) return;
    f32x4 a = ((const f32x4*)src)[2 * i];
    f32x4 b = ((const f32x4*)src)[2 * i + 1];
    bf16x8 o;
#pragma unroll
    for (int j = 0; j < 4; ++j) o[j] = (short)f2bf(a[j] * scale);
#pragma unroll
    for (int j = 0; j < 4; ++j) o[4 + j] = (short)f2bf(b[j] * scale);
    ((bf16x8*)dst)[i] = o;
}

// ---------------- prologue: V [h][kv][d] fp32 -> V^T [h][d][kv] bf16 ----------------
__global__ void transposeV(const float* __restrict__ V, ushort_t* __restrict__ Vt)
{
    __shared__ float tile[64][65];
    const int tid = threadIdx.x;
    const int hh = blockIdx.x >> 5;
    const int kt = blockIdx.x & 31;

#pragma unroll
    for (int it = 0; it < 4; ++it) {
        int m = it * 256 + tid;
        int r = m >> 4, c4 = m & 15;
        f32x4 v = *(const f32x4*)(V + ((size_t)(hh * SS + kt * 64 + r)) * DD + c4 * 4);
#pragma unroll
        for (int j = 0; j < 4; ++j) tile[r][c4 * 4 + j] = v[j];
    }
    __syncthreads();
#pragma unroll
    for (int it = 0; it < 2; ++it) {
        int m = it * 256 + tid;
        int d = m >> 3, c8 = m & 7;
        bf16x8 o;
#pragma unroll
        for (int j = 0; j < 8; ++j) o[j] = (short)f2bf(tile[c8 * 8 + j][d]);
        *(bf16x8*)(Vt + ((size_t)hh * DD + d) * SS + kt * 64 + c8 * 8) = o;
    }
}

// ---------------- main: barrier-free K/V-from-L2, kv-split across 4 waves ----------------
__global__ __launch_bounds__(256, 3)
void attn_main2(const float* __restrict__ gQ, const ushort_t* __restrict__ Kbf,
                const ushort_t* __restrict__ Vtbf, float* __restrict__ gO,
                float* __restrict__ gP)
{
    __shared__ float lsm[4 * 32];          // per-wave partial denominators
    __shared__ float osm[4 * 64 * 33];     // per-wave partial O^T [w][d][q], padded

    const int tid  = threadIdx.x;
    const int lane = tid & 63;
    const int wave = tid >> 6;
    const int lo5  = lane & 31;
    const int hi   = lane >> 5;

    const int bid  = blockIdx.x;
    const int wg   = (bid & 7) * 256 + (bid >> 3);   // XCD-contiguous: 4 heads per XCD
    const int head = wg >> 6;
    const int q0b  = (wg & 63) * 32;

    const float*    Qh = gQ   + (size_t)head * SS * DD;
    const ushort_t* Kh = Kbf  + (size_t)head * SS * DD;
    const ushort_t* Vh = Vtbf + (size_t)head * DD * SS;   // [d][kv]
    float* Oh = gO + (size_t)head * SS * DD;
    float* Ph = gP + (size_t)head * SS * SS;

    const float SCALE = 0.125f * 1.44269504088896340736f; // (1/sqrt(64)) * log2(e)

    // ---- Q B-fragments from fp32 global, scale folded ----
    const int qrow = q0b + lo5;
    bf16x8 qf[4];
#pragma unroll
    for (int ks = 0; ks < 4; ++ks) {
        const float* qp = Qh + (size_t)qrow * DD + ks * 16 + hi * 8;
        f32x4 a = *(const f32x4*)(qp);
        f32x4 b = *(const f32x4*)(qp + 4);
        bf16x8 o;
#pragma unroll
        for (int j = 0; j < 4; ++j) o[j] = (short)f2bf(a[j] * SCALE);
#pragma unroll
        for (int j = 0; j < 4; ++j) o[4 + j] = (short)f2bf(b[j] * SCALE);
        qf[ks] = o;
    }

    const int kv_base = wave * 512;        // this wave's kv range [kv_base, kv_base+512)

    // ================= PASS A: denominator (max-free) =================
    float ls0 = 0.f, ls1 = 0.f;
#pragma unroll 2
    for (int t = 0; t < 8; ++t) {
        int kv0 = kv_base + t * 64;
#pragma unroll
        for (int sub = 0; sub < 2; ++sub) {
            f32x16 acc = zero16();
            const ushort_t* kp = Kh + (size_t)(kv0 + sub * 32 + lo5) * DD + hi * 8;
#pragma unroll
            for (int ks = 0; ks < 4; ++ks) {
                bf16x8 kf = *(const bf16x8*)(kp + ks * 16);
                acc = __builtin_amdgcn_mfma_f32_32x32x16_bf16(kf, qf[ks], acc, 0, 0, 0);
            }
#pragma unroll
            for (int r = 0; r < 16; r += 2) {
                ls0 += __builtin_exp2f(acc[r]);
                ls1 += __builtin_exp2f(acc[r + 1]);
            }
        }
    }
    float lsum = ls0 + ls1;
    lsum += __shfl_xor(lsum, 32);
    lsm[wave * 32 + lo5] = lsum;           // both halves write same value
    __syncthreads();
    const float rinv = 1.0f / (lsm[lo5] + lsm[32 + lo5] + lsm[64 + lo5] + lsm[96 + lo5]);

    // ================= PASS B: scores, P write, PV =================
    f32x16 o0 = zero16(), o1 = zero16();
    float* prow_base = Ph + (size_t)qrow * SS;

#pragma unroll 2
    for (int t = 0; t < 8; ++t) {
        int kv0 = kv_base + t * 64;
#pragma unroll
        for (int sub = 0; sub < 2; ++sub) {
            f32x16 acc = zero16();
            const ushort_t* kp = Kh + (size_t)(kv0 + sub * 32 + lo5) * DD + hi * 8;
#pragma unroll
            for (int ks = 0; ks < 4; ++ks) {
                bf16x8 kf = *(const bf16x8*)(kp + ks * 16);
                acc = __builtin_amdgcn_mfma_f32_32x32x16_bf16(kf, qf[ks], acc, 0, 0, 0);
            }
            float pr[16];
#pragma unroll
            for (int r = 0; r < 16; ++r) pr[r] = __builtin_exp2f(acc[r]);

            // store normalized P (normal stores: 16B partials merge into full
            // 128B lines in L2 before writeback — nt hint caused 2x write amp)
            float* prow = prow_base + kv0 + sub * 32;
#pragma unroll
            for (int g = 0; g < 4; ++g) {
                f32x4 st = { pr[4*g+0] * rinv, pr[4*g+1] * rinv, pr[4*g+2] * rinv, pr[4*g+3] * rinv };
                *(f32x4*)(prow + g * 8 + hi * 4) = st;
            }

            // pack unnormalized p to bf16 pairs
            unsigned u[8];
#pragma unroll
            for (int j = 0; j < 8; ++j)
                u[j] = (unsigned)f2bf(pr[2*j]) | ((unsigned)f2bf(pr[2*j+1]) << 16);

            // assemble P^T B-frags via half-wave exchange
            unsigned s0 = __shfl_xor(u[0], 32), s1 = __shfl_xor(u[1], 32);
            unsigned s2 = __shfl_xor(u[2], 32), s3 = __shfl_xor(u[3], 32);
            unsigned s4 = __shfl_xor(u[4], 32), s5 = __shfl_xor(u[5], 32);
            unsigned s6 = __shfl_xor(u[6], 32), s7 = __shfl_xor(u[7], 32);
            PFrag pf0, pf1;
            pf0.w[0] = hi ? s2 : u[0];  pf0.w[1] = hi ? s3 : u[1];
            pf0.w[2] = hi ? u[2] : s0;  pf0.w[3] = hi ? u[3] : s1;
            pf1.w[0] = hi ? s6 : u[4];  pf1.w[1] = hi ? s7 : u[5];
            pf1.w[2] = hi ? u[6] : s4;  pf1.w[3] = hi ? u[7] : s5;

            // PV: O^T[64d][32q] += V^T * P^T, V^T frags straight from L2
#pragma unroll
            for (int dt = 0; dt < 2; ++dt) {
                const ushort_t* vp = Vh + (size_t)(dt * 32 + lo5) * SS + kv0 + sub * 32 + hi * 8;
                bf16x8 vf0 = *(const bf16x8*)(vp);
                bf16x8 vf1 = *(const bf16x8*)(vp + 16);
                f32x16& od = dt ? o1 : o0;
                od = __builtin_amdgcn_mfma_f32_32x32x16_bf16(vf0, pf0.v, od, 0, 0, 0);
                od = __builtin_amdgcn_mfma_f32_32x32x16_bf16(vf1, pf1.v, od, 0, 0, 0);
            }
        }
    }

    // ---- write per-wave O^T partials to LDS: reg 4g+j of tile dt is d = dt*32+8g+4hi+j ----
#pragma unroll
    for (int dt = 0; dt < 2; ++dt) {
        const f32x16& od = dt ? o1 : o0;
#pragma unroll
        for (int g = 0; g < 4; ++g) {
#pragma unroll
            for (int j = 0; j < 4; ++j) {
                int d = dt * 32 + g * 8 + hi * 4 + j;
                osm[(wave * 64 + d) * 33 + lo5] = od[4 * g + j];
            }
        }
    }
    __syncthreads();

    // ---- reduce 4 wave partials, normalize, store O ----
    {
        const int q  = tid >> 3;
        const int d0 = (tid & 7) * 8;
        const float rq = 1.0f / (lsm[q] + lsm[32 + q] + lsm[64 + q] + lsm[96 + q]);
        float out[8];
#pragma unroll
        for (int i = 0; i < 8; ++i) {
            int d = d0 + i;
            out[i] = (osm[(0 * 64 + d) * 33 + q] + osm[(1 * 64 + d) * 33 + q] +
                      osm[(2 * 64 + d) * 33 + q] + osm[(3 * 64 + d) * 33 + q]) * rq;
        }
        float* op = Oh + (size_t)(q0b + q) * DD + d0;
        f32x4 a = { out[0], out[1], out[2], out[3] };
        f32x4 b = { out[4], out[5], out[6], out[7] };
        *(f32x4*)(op)     = a;
        *(f32x4*)(op + 4) = b;
    }
}

// ================= fallback (no-ws path) =================
__global__ __launch_bounds__(256, 2)
void attn_fused(const float* __restrict__ gQ, const float* __restrict__ gK,
                const float* __restrict__ gV, float* __restrict__ gO,
                float* __restrict__ gP)
{
    __shared__ unsigned short Qs[128 * DD];
    __shared__ unsigned short Ks[64 * DD];
    __shared__ unsigned short Vt[DD * 64];

    const int tid  = threadIdx.x;
    const int lane = tid & 63;
    const int wave = tid >> 6;
    const int lo5  = lane & 31;
    const int hi   = lane >> 5;

    const int head = blockIdx.x >> 4;
    const int q0b  = (blockIdx.x & 15) * 128;

    const float* Qh = gQ + (size_t)head * SS * DD;
    const float* Kh = gK + (size_t)head * SS * DD;
    const float* Vh = gV + (size_t)head * SS * DD;
    float* Oh = gO + (size_t)head * SS * DD;
    float* Ph = gP + (size_t)head * SS * SS;

    const float SCALE = 0.125f * 1.44269504088896340736f;

#pragma unroll
    for (int it = 0; it < 8; ++it) {
        int m = it * 256 + tid;
        int q = m >> 4, d4 = m & 15;
        f32x4 v = *(const f32x4*)(Qh + (size_t)(q0b + q) * DD + d4 * 4);
        unsigned a = (unsigned)f2bf(v.x * SCALE) | ((unsigned)f2bf(v.y * SCALE) << 16);
        unsigned b = (unsigned)f2bf(v.z * SCALE) | ((unsigned)f2bf(v.w * SCALE) << 16);
        u32x2 w; w.x = a; w.y = b;
        *(u32x2*)(Qs + q * 64 + d4 * 4) = w;
    }
    __syncthreads();

    const int qrow = wave * 32 + lo5;
    bf16x8 qf[4];
#pragma unroll
    for (int ks = 0; ks < 4; ++ks)
        qf[ks] = *(const bf16x8*)(Qs + qrow * 64 + ks * 16 + hi * 8);

    auto stageK = [&](int kv0) {
#pragma unroll
        for (int it = 0; it < 4; ++it) {
            int m = it * 256 + tid;
            int kv = m >> 4, d4 = m & 15;
            f32x4 v = *(const f32x4*)(Kh + (size_t)(kv0 + kv) * DD + d4 * 4);
            unsigned a = (unsigned)f2bf(v.x) | ((unsigned)f2bf(v.y) << 16);
            unsigned b = (unsigned)f2bf(v.z) | ((unsigned)f2bf(v.w) << 16);
            int c16 = (d4 >> 1) ^ (kv & 7);
            u32x2 w; w.x = a; w.y = b;
            *(u32x2*)(Ks + kv * 64 + c16 * 8 + (d4 & 1) * 4) = w;
        }
    };
    auto stageV = [&](int kv0) {
#pragma unroll
        for (int it = 0; it < 2; ++it) {
            int m = it * 256 + tid;
            int kv2 = m >> 4, d4 = m & 15;
            const float* p0 = Vh + (size_t)(kv0 + kv2 * 2) * DD + d4 * 4;
            f32x4 v0 = *(const f32x4*)(p0);
            f32x4 v1 = *(const f32x4*)(p0 + DD);
#pragma unroll
            for (int c = 0; c < 4; ++c) {
                int d = d4 * 4 + c;
                unsigned u = (unsigned)f2bf(v0[c]) | ((unsigned)f2bf(v1[c]) << 16);
                int c16 = (kv2 >> 2) ^ (d & 7);
                *(unsigned*)(Vt + d * 64 + c16 * 8 + (kv2 & 3) * 2) = u;
            }
        }
    };

    float m_run = -1e30f, l_run = 0.f;
    for (int kv0 = 0; kv0 < SS; kv0 += 64) {
        __syncthreads();
        stageK(kv0);
        __syncthreads();
#pragma unroll
        for (int sub = 0; sub < 2; ++sub) {
            f32x16 acc = zero16();
            int kvl = sub * 32 + lo5;
#pragma unroll
            for (int ks = 0; ks < 4; ++ks) {
                bf16x8 kf = *(const bf16x8*)(Ks + kvl * 64 + ((((ks * 2) + hi) ^ (kvl & 7)) << 3));
                acc = __builtin_amdgcn_mfma_f32_32x32x16_bf16(kf, qf[ks], acc, 0, 0, 0);
            }
            float tm = acc[0];
#pragma unroll
            for (int r = 1; r < 16; ++r) tm = fmaxf(tm, acc[r]);
            float mn = fmaxf(m_run, tm);
            float sum = 0.f;
#pragma unroll
            for (int r = 0; r < 16; ++r) sum += __builtin_exp2f(acc[r] - mn);
            l_run = l_run * __builtin_exp2f(m_run - mn) + sum;
            m_run = mn;
        }
    }
    {
        float mo = __shfl_xor(m_run, 32);
        float mf = fmaxf(m_run, mo);
        float la = l_run * __builtin_exp2f(m_run - mf);
        float lb = __shfl_xor(la, 32);
        l_run = la + lb;
        m_run = mf;
    }
    const float rinv = 1.0f / l_run;

    f32x16 o0 = zero16(), o1 = zero16();
    const int qg = q0b + wave * 32 + lo5;
    float* prow_base = Ph + (size_t)qg * SS;

    for (int kv0 = 0; kv0 < SS; kv0 += 64) {
        __syncthreads();
        stageK(kv0);
        stageV(kv0);
        __syncthreads();
#pragma unroll
        for (int sub = 0; sub < 2; ++sub) {
            f32x16 acc = zero16();
            int kvl = sub * 32 + lo5;
#pragma unroll
            for (int ks = 0; ks < 4; ++ks) {
                bf16x8 kf = *(const bf16x8*)(Ks + kvl * 64 + ((((ks * 2) + hi) ^ (kvl & 7)) << 3));
                acc = __builtin_amdgcn_mfma_f32_32x32x16_bf16(kf, qf[ks], acc, 0, 0, 0);
            }
            float pr[16];
#pragma unroll
            for (int r = 0; r < 16; ++r) pr[r] = __builtin_exp2f(acc[r] - m_run);

            float* prow = prow_base + kv0 + sub * 32;
#pragma unroll
            for (int g = 0; g < 4; ++g) {
                f32x4 st = { pr[4*g+0] * rinv, pr[4*g+1] * rinv, pr[4*g+2] * rinv, pr[4*g+3] * rinv };
                *(f32x4*)(prow + g * 8 + hi * 4) = st;
            }

            unsigned u[8];
#pragma unroll
            for (int j = 0; j < 8; ++j)
                u[j] = (unsigned)f2bf(pr[2*j]) | ((unsigned)f2bf(pr[2*j+1]) << 16);

            unsigned s0 = __shfl_xor(u[0], 32), s1 = __shfl_xor(u[1], 32);
            unsigned s2 = __shfl_xor(u[2], 32), s3 = __shfl_xor(u[3], 32);
            unsigned s4 = __shfl_xor(u[4], 32), s5 = __shfl_xor(u[5], 32);
            unsigned s6 = __shfl_xor(u[6], 32), s7 = __shfl_xor(u[7], 32);
            PFrag pf0, pf1;
            pf0.w[0] = hi ? s2 : u[0];  pf0.w[1] = hi ? s3 : u[1];
            pf0.w[2] = hi ? u[2] : s0;  pf0.w[3] = hi ? u[3] : s1;
            pf1.w[0] = hi ? s6 : u[4];  pf1.w[1] = hi ? s7 : u[5];
            pf1.w[2] = hi ? u[6] : s4;  pf1.w[3] = hi ? u[7] : s5;

#pragma unroll
            for (int dt = 0; dt < 2; ++dt) {
                int drow = dt * 32 + lo5;
                int c0 = ((sub * 4) + 0 + hi) ^ (drow & 7);
                int c1 = ((sub * 4) + 2 + hi) ^ (drow & 7);
                bf16x8 vf0 = *(const bf16x8*)(Vt + drow * 64 + (c0 << 3));
                bf16x8 vf1 = *(const bf16x8*)(Vt + drow * 64 + (c1 << 3));
                f32x16& od = dt ? o1 : o0;
                od = __builtin_amdgcn_mfma_f32_32x32x16_bf16(vf0, pf0.v, od, 0, 0, 0);
                od = __builtin_amdgcn_mfma_f32_32x32x16_bf16(vf1, pf1.v, od, 0, 0, 0);
            }
        }
    }

    float* orow = Oh + (size_t)qg * DD;
#pragma unroll
    for (int dt = 0; dt < 2; ++dt) {
        const f32x16& od = dt ? o1 : o0;
#pragma unroll
        for (int g = 0; g < 4; ++g) {
            f32x4 st = { od[4*g+0] * rinv, od[4*g+1] * rinv, od[4*g+2] * rinv, od[4*g+3] * rinv };
            *(f32x4*)(orow + dt * 32 + g * 8 + hi * 4) = st;
        }
    }
}

extern "C" void kernel_launch(void* const* d_in, const int* in_sizes, int n_in,
                              void* d_out, int out_size, void* d_ws, size_t ws_size,
                              hipStream_t stream) {
    const float* Q = (const float*)d_in[0];
    const float* K = (const float*)d_in[1];
    const float* V = (const float*)d_in[2];
    float* O = (float*)d_out;
    float* P = O + (size_t)2 * 16 * SS * DD;

    const size_t HD = (size_t)32 * SS * DD;           // elems per tensor
    const size_t need = 2 * HD * sizeof(ushort_t);    // K bf16 + V^T bf16 ≈ 16.8 MB

    if (ws_size >= need) {
        ushort_t* Kbf  = (ushort_t*)d_ws;
        ushort_t* Vtbf = Kbf + HD;
        int n8 = (int)(HD / 8);
        hipLaunchKernelGGL(cvt_bf16, dim3(n8 / 256), dim3(256), 0, stream, K, Kbf, n8, 1.0f);
        hipLaunchKernelGGL(transposeV, dim3(1024), dim3(256), 0, stream, V, Vtbf);
        hipLaunchKernelGGL(attn_main2, dim3(2048), dim3(256), 0, stream, Q, Kbf, Vtbf, O, P);
    } else {
        hipLaunchKernelGGL(attn_fused, dim3(512), dim3(256), 0, stream, Q, K, V, O, P);
    }
}

// Round 6
// 212.274 us; speedup vs baseline: 2.4368x; 1.3006x over previous
//
#include <hip/hip_runtime.h>

#define SS 2048
#define DD 64
#define QB 64       // q rows per block (2 q-tiles x 32)
#define KVB 64      // kv rows per staged tile
#define NT (SS / KVB)

typedef unsigned short ushort_t;
typedef __attribute__((ext_vector_type(4)))  float f32x4;
typedef __attribute__((ext_vector_type(16))) float f32x16;
typedef __attribute__((ext_vector_type(8)))  short bf16x8;
typedef __attribute__((ext_vector_type(2)))  unsigned int u32x2;

static __device__ __forceinline__ unsigned short f2bf(float f) {
    unsigned u = __builtin_bit_cast(unsigned, f);
    u += 0x7FFFu + ((u >> 16) & 1u);
    return (unsigned short)(u >> 16);
}

static __device__ __forceinline__ f32x16 zero16() {
    f32x16 z;
#pragma unroll
    for (int i = 0; i < 16; ++i) z[i] = 0.f;
    return z;
}

union PFrag { bf16x8 v; unsigned w[4]; };

#define GLL16(src, dst) \
    __builtin_amdgcn_global_load_lds((const __attribute__((address_space(1))) void*)(src), \
                                     (__attribute__((address_space(3))) void*)(dst), 16, 0, 0)

// ---------------- prologue: fp32 -> bf16 ----------------
__global__ void cvt_bf16(const float* __restrict__ src, ushort_t* __restrict__ dst,
                         int n8, float scale)
{
    int i = blockIdx.x * blockDim.x + threadIdx.x;
    if (i >= n8) return;
    f32x4 a = ((const f32x4*)src)[2 * i];
    f32x4 b = ((const f32x4*)src)[2 * i + 1];
    bf16x8 o;
#pragma unroll
    for (int j = 0; j < 4; ++j) o[j] = (short)f2bf(a[j] * scale);
#pragma unroll
    for (int j = 0; j < 4; ++j) o[4 + j] = (short)f2bf(b[j] * scale);
    ((bf16x8*)dst)[i] = o;
}

// ---------------- prologue: V [h][kv][d] fp32 -> V^T [h][d][kv] bf16 ----------------
__global__ void transposeV(const float* __restrict__ V, ushort_t* __restrict__ Vt)
{
    __shared__ float tile[64][65];
    const int tid = threadIdx.x;
    const int hh = blockIdx.x >> 5;
    const int kt = blockIdx.x & 31;

#pragma unroll
    for (int it = 0; it < 4; ++it) {
        int m = it * 256 + tid;
        int r = m >> 4, c4 = m & 15;
        f32x4 v = *(const f32x4*)(V + ((size_t)(hh * SS + kt * 64 + r)) * DD + c4 * 4);
#pragma unroll
        for (int j = 0; j < 4; ++j) tile[r][c4 * 4 + j] = v[j];
    }
    __syncthreads();
#pragma unroll
    for (int it = 0; it < 2; ++it) {
        int m = it * 256 + tid;
        int d = m >> 3, c8 = m & 7;
        bf16x8 o;
#pragma unroll
        for (int j = 0; j < 8; ++j) o[j] = (short)f2bf(tile[c8 * 8 + j][d]);
        *(bf16x8*)(Vt + ((size_t)hh * DD + d) * SS + kt * 64 + c8 * 8) = o;
    }
}

// ---------------- main: QB=64, 4 blocks/CU, LDS dbuf, plain barriers ----------------
__global__ __launch_bounds__(256, 4)
void attn_main4(const float* __restrict__ gQ, const ushort_t* __restrict__ Kbf,
                const ushort_t* __restrict__ Vtbf, float* __restrict__ gO,
                float* __restrict__ gP)
{
    __shared__ float lsm[4][32];                               // per-wave partial denoms
    __shared__ __attribute__((aligned(16))) char shraw[33792]; // union: stage / osm
    ushort_t* stage = (ushort_t*)shraw;   // [2 buf][ K:4096 | V:4096 ] elems
    float*    osm   = (float*)shraw;      // [4][64][33] after main loop

    const int tid  = threadIdx.x;
    const int lane = tid & 63;
    const int wave = tid >> 6;
    const int lo5  = lane & 31;
    const int hi   = lane >> 5;
    const int qs   = wave >> 1;          // q sub-tile (0,1)
    const int sub  = wave & 1;           // kv sub within 64-tile (0,1)

    const int bid  = blockIdx.x;
    const int wg   = (bid & 7) * 128 + (bid >> 3);  // XCD-contiguous (4 heads/XCD)
    const int head = wg >> 5;
    const int q0b  = (wg & 31) * QB;

    const float*    Qh = gQ   + (size_t)head * SS * DD;
    const ushort_t* Kh = Kbf  + (size_t)head * SS * DD;
    const ushort_t* Vh = Vtbf + (size_t)head * DD * SS;   // [d][kv]
    float* Oh = gO + (size_t)head * SS * DD;
    float* Ph = gP + (size_t)head * SS * SS;

    const float SCALE = 0.125f * 1.44269504088896340736f; // (1/sqrt(64)) * log2(e)

    // ---- Q B-fragments from fp32 global (scale+log2e folded) ----
    const int qrow = q0b + qs * 32 + lo5;
    bf16x8 qf[4];
#pragma unroll
    for (int ks = 0; ks < 4; ++ks) {
        const float* qp = Qh + (size_t)qrow * DD + ks * 16 + hi * 8;
        f32x4 a = *(const f32x4*)(qp);
        f32x4 b = *(const f32x4*)(qp + 4);
        bf16x8 o;
#pragma unroll
        for (int j = 0; j < 4; ++j) o[j] = (short)f2bf(a[j] * SCALE);
#pragma unroll
        for (int j = 0; j < 4; ++j) o[4 + j] = (short)f2bf(b[j] * SCALE);
        qf[ks] = o;
    }

    // ---- staging addresses (source pre-swizzled, LDS dest linear) ----
    const int lgrp = lane >> 3;              // 0..7
    const int lchk = (lane & 7) ^ lgrp;      // involution chunk swizzle
    const ushort_t* srcK[2]; const ushort_t* srcV[2];
#pragma unroll
    for (int j = 0; j < 2; ++j) {
        int W = wave * 2 + j;                // 0..7 row-group
        srcK[j] = Kh + (size_t)(W * 8 + lgrp) * DD + lchk * 8;
        srcV[j] = Vh + (size_t)(W * 8 + lgrp) * SS + lchk * 8;
    }
    const int kvl = sub * 32 + lo5;          // this wave's K row in tile

    // ================= PASS A: denominator (max-free) =================
#pragma unroll
    for (int j = 0; j < 2; ++j) GLL16(srcK[j], stage + (wave * 2 + j) * 512);
    __syncthreads();

    float ls0 = 0.f, ls1 = 0.f;
    for (int t = 0; t < NT; ++t) {
        const int buf = t & 1;
        if (t + 1 < NT) {
#pragma unroll
            for (int j = 0; j < 2; ++j)
                GLL16(srcK[j] + (size_t)(t + 1) * KVB * DD,
                      stage + (buf ^ 1) * 8192 + (wave * 2 + j) * 512);
        }
        const ushort_t* Ksb = stage + buf * 8192;
        f32x16 acc = zero16();
#pragma unroll
        for (int ks = 0; ks < 4; ++ks) {
            bf16x8 kf = *(const bf16x8*)(Ksb + kvl * 64 + ((((ks * 2) + hi) ^ (kvl & 7)) << 3));
            acc = __builtin_amdgcn_mfma_f32_32x32x16_bf16(kf, qf[ks], acc, 0, 0, 0);
        }
#pragma unroll
        for (int r = 0; r < 16; r += 2) {
            ls0 += __builtin_exp2f(acc[r]);
            ls1 += __builtin_exp2f(acc[r + 1]);
        }
        __syncthreads();
    }
    float lsum = ls0 + ls1;
    lsum += __shfl_xor(lsum, 32);
    lsm[wave][lo5] = lsum;
    __syncthreads();
    const float rinv = 1.0f / (lsm[qs * 2][lo5] + lsm[qs * 2 + 1][lo5]);

    // ================= PASS B: scores, P write, PV =================
    f32x16 o0 = zero16(), o1 = zero16();
    float* prow_base = Ph + (size_t)qrow * SS;

#pragma unroll
    for (int j = 0; j < 2; ++j) {
        GLL16(srcK[j], stage + (wave * 2 + j) * 512);
        GLL16(srcV[j], stage + 4096 + (wave * 2 + j) * 512);
    }
    __syncthreads();

    for (int t = 0; t < NT; ++t) {
        const int buf = t & 1;
        if (t + 1 < NT) {
#pragma unroll
            for (int j = 0; j < 2; ++j) {
                GLL16(srcK[j] + (size_t)(t + 1) * KVB * DD,
                      stage + (buf ^ 1) * 8192 + (wave * 2 + j) * 512);
                GLL16(srcV[j] + (size_t)(t + 1) * KVB,
                      stage + (buf ^ 1) * 8192 + 4096 + (wave * 2 + j) * 512);
            }
        }
        const ushort_t* Ksb = stage + buf * 8192;
        const ushort_t* Vtb = Ksb + 4096;

        f32x16 acc = zero16();
#pragma unroll
        for (int ks = 0; ks < 4; ++ks) {
            bf16x8 kf = *(const bf16x8*)(Ksb + kvl * 64 + ((((ks * 2) + hi) ^ (kvl & 7)) << 3));
            acc = __builtin_amdgcn_mfma_f32_32x32x16_bf16(kf, qf[ks], acc, 0, 0, 0);
        }
        float pr[16];
#pragma unroll
        for (int r = 0; r < 16; ++r) pr[r] = __builtin_exp2f(acc[r]);

        // normalized P store
        float* prow = prow_base + t * KVB + sub * 32;
#pragma unroll
        for (int g = 0; g < 4; ++g) {
            f32x4 st = { pr[4*g+0] * rinv, pr[4*g+1] * rinv, pr[4*g+2] * rinv, pr[4*g+3] * rinv };
            *(f32x4*)(prow + g * 8 + hi * 4) = st;
        }

        // rounding bf16 pack (R2-proven)
        unsigned u[8];
#pragma unroll
        for (int j = 0; j < 8; ++j)
            u[j] = (unsigned)f2bf(pr[2*j]) | ((unsigned)f2bf(pr[2*j+1]) << 16);

        // assemble P^T B-frags via half-wave exchange
        unsigned s0 = __shfl_xor(u[0], 32), s1 = __shfl_xor(u[1], 32);
        unsigned s2 = __shfl_xor(u[2], 32), s3 = __shfl_xor(u[3], 32);
        unsigned s4 = __shfl_xor(u[4], 32), s5 = __shfl_xor(u[5], 32);
        unsigned s6 = __shfl_xor(u[6], 32), s7 = __shfl_xor(u[7], 32);
        PFrag pf0, pf1;
        pf0.w[0] = hi ? s2 : u[0];  pf0.w[1] = hi ? s3 : u[1];
        pf0.w[2] = hi ? u[2] : s0;  pf0.w[3] = hi ? u[3] : s1;
        pf1.w[0] = hi ? s6 : u[4];  pf1.w[1] = hi ? s7 : u[5];
        pf1.w[2] = hi ? u[6] : s4;  pf1.w[3] = hi ? u[7] : s5;

        // PV: O^T[64d][32q] += V^T * P^T
#pragma unroll
        for (int dt = 0; dt < 2; ++dt) {
            int drow = dt * 32 + lo5;
            int c0 = ((sub * 4) + 0 + hi) ^ (drow & 7);
            int c1 = ((sub * 4) + 2 + hi) ^ (drow & 7);
            bf16x8 vf0 = *(const bf16x8*)(Vtb + drow * 64 + (c0 << 3));
            bf16x8 vf1 = *(const bf16x8*)(Vtb + drow * 64 + (c1 << 3));
            f32x16& od = dt ? o1 : o0;
            od = __builtin_amdgcn_mfma_f32_32x32x16_bf16(vf0, pf0.v, od, 0, 0, 0);
            od = __builtin_amdgcn_mfma_f32_32x32x16_bf16(vf1, pf1.v, od, 0, 0, 0);
        }

        __syncthreads();
    }

    // ================= epilogue: 2-way O reduce through reused LDS =================
#pragma unroll
    for (int dt = 0; dt < 2; ++dt) {
        const f32x16& od = dt ? o1 : o0;
#pragma unroll
        for (int g = 0; g < 4; ++g) {
#pragma unroll
            for (int j = 0; j < 4; ++j) {
                int d = dt * 32 + g * 8 + hi * 4 + j;
                osm[(wave * 64 + d) * 33 + lo5] = od[4 * g + j];
            }
        }
    }
    __syncthreads();
    {
        const int p  = tid >> 7;            // q sub-tile
        const int q  = (tid >> 2) & 31;
        const int d0 = (tid & 3) * 16;
        const float rq = 1.0f / (lsm[2 * p][q] + lsm[2 * p + 1][q]);
        float* op = Oh + (size_t)(q0b + p * 32 + q) * DD + d0;
#pragma unroll
        for (int v4 = 0; v4 < 4; ++v4) {
            f32x4 st;
#pragma unroll
            for (int j = 0; j < 4; ++j) {
                int d = d0 + v4 * 4 + j;
                st[j] = (osm[((2 * p) * 64 + d) * 33 + q] +
                         osm[((2 * p + 1) * 64 + d) * 33 + q]) * rq;
            }
            *(f32x4*)(op + v4 * 4) = st;
        }
    }
}

// ================= fallback (no-ws path) =================
__global__ __launch_bounds__(256, 2)
void attn_fused(const float* __restrict__ gQ, const float* __restrict__ gK,
                const float* __restrict__ gV, float* __restrict__ gO,
                float* __restrict__ gP)
{
    __shared__ unsigned short Qs[128 * DD];
    __shared__ unsigned short Ks[64 * DD];
    __shared__ unsigned short Vt[DD * 64];

    const int tid  = threadIdx.x;
    const int lane = tid & 63;
    const int wave = tid >> 6;
    const int lo5  = lane & 31;
    const int hi   = lane >> 5;

    const int head = blockIdx.x >> 4;
    const int q0b  = (blockIdx.x & 15) * 128;

    const float* Qh = gQ + (size_t)head * SS * DD;
    const float* Kh = gK + (size_t)head * SS * DD;
    const float* Vh = gV + (size_t)head * SS * DD;
    float* Oh = gO + (size_t)head * SS * DD;
    float* Ph = gP + (size_t)head * SS * SS;

    const float SCALE = 0.125f * 1.44269504088896340736f;

#pragma unroll
    for (int it = 0; it < 8; ++it) {
        int m = it * 256 + tid;
        int q = m >> 4, d4 = m & 15;
        f32x4 v = *(const f32x4*)(Qh + (size_t)(q0b + q) * DD + d4 * 4);
        unsigned a = (unsigned)f2bf(v.x * SCALE) | ((unsigned)f2bf(v.y * SCALE) << 16);
        unsigned b = (unsigned)f2bf(v.z * SCALE) | ((unsigned)f2bf(v.w * SCALE) << 16);
        u32x2 w; w.x = a; w.y = b;
        *(u32x2*)(Qs + q * 64 + d4 * 4) = w;
    }
    __syncthreads();

    const int qrow = wave * 32 + lo5;
    bf16x8 qf[4];
#pragma unroll
    for (int ks = 0; ks < 4; ++ks)
        qf[ks] = *(const bf16x8*)(Qs + qrow * 64 + ks * 16 + hi * 8);

    auto stageK = [&](int kv0) {
#pragma unroll
        for (int it = 0; it < 4; ++it) {
            int m = it * 256 + tid;
            int kv = m >> 4, d4 = m & 15;
            f32x4 v = *(const f32x4*)(Kh + (size_t)(kv0 + kv) * DD + d4 * 4);
            unsigned a = (unsigned)f2bf(v.x) | ((unsigned)f2bf(v.y) << 16);
            unsigned b = (unsigned)f2bf(v.z) | ((unsigned)f2bf(v.w) << 16);
            int c16 = (d4 >> 1) ^ (kv & 7);
            u32x2 w; w.x = a; w.y = b;
            *(u32x2*)(Ks + kv * 64 + c16 * 8 + (d4 & 1) * 4) = w;
        }
    };
    auto stageV = [&](int kv0) {
#pragma unroll
        for (int it = 0; it < 2; ++it) {
            int m = it * 256 + tid;
            int kv2 = m >> 4, d4 = m & 15;
            const float* p0 = Vh + (size_t)(kv0 + kv2 * 2) * DD + d4 * 4;
            f32x4 v0 = *(const f32x4*)(p0);
            f32x4 v1 = *(const f32x4*)(p0 + DD);
#pragma unroll
            for (int c = 0; c < 4; ++c) {
                int d = d4 * 4 + c;
                unsigned u = (unsigned)f2bf(v0[c]) | ((unsigned)f2bf(v1[c]) << 16);
                int c16 = (kv2 >> 2) ^ (d & 7);
                *(unsigned*)(Vt + d * 64 + c16 * 8 + (kv2 & 3) * 2) = u;
            }
        }
    };

    float m_run = -1e30f, l_run = 0.f;
    for (int kv0 = 0; kv0 < SS; kv0 += 64) {
        __syncthreads();
        stageK(kv0);
        __syncthreads();
#pragma unroll
        for (int sub = 0; sub < 2; ++sub) {
            f32x16 acc = zero16();
            int kvl = sub * 32 + lo5;
#pragma unroll
            for (int ks = 0; ks < 4; ++ks) {
                bf16x8 kf = *(const bf16x8*)(Ks + kvl * 64 + ((((ks * 2) + hi) ^ (kvl & 7)) << 3));
                acc = __builtin_amdgcn_mfma_f32_32x32x16_bf16(kf, qf[ks], acc, 0, 0, 0);
            }
            float tm = acc[0];
#pragma unroll
            for (int r = 1; r < 16; ++r) tm = fmaxf(tm, acc[r]);
            float mn = fmaxf(m_run, tm);
            float sum = 0.f;
#pragma unroll
            for (int r = 0; r < 16; ++r) sum += __builtin_exp2f(acc[r] - mn);
            l_run = l_run * __builtin_exp2f(m_run - mn) + sum;
            m_run = mn;
        }
    }
    {
        float mo = __shfl_xor(m_run, 32);
        float mf = fmaxf(m_run, mo);
        float la = l_run * __builtin_exp2f(m_run - mf);
        float lb = __shfl_xor(la, 32);
        l_run = la + lb;
        m_run = mf;
    }
    const float rinv = 1.0f / l_run;

    f32x16 o0 = zero16(), o1 = zero16();
    const int qg = q0b + wave * 32 + lo5;
    float* prow_base = Ph + (size_t)qg * SS;

    for (int kv0 = 0; kv0 < SS; kv0 += 64) {
        __syncthreads();
        stageK(kv0);
        stageV(kv0);
        __syncthreads();
#pragma unroll
        for (int sub = 0; sub < 2; ++sub) {
            f32x16 acc = zero16();
            int kvl = sub * 32 + lo5;
#pragma unroll
            for (int ks = 0; ks < 4; ++ks) {
                bf16x8 kf = *(const bf16x8*)(Ks + kvl * 64 + ((((ks * 2) + hi) ^ (kvl & 7)) << 3));
                acc = __builtin_amdgcn_mfma_f32_32x32x16_bf16(kf, qf[ks], acc, 0, 0, 0);
            }
            float pr[16];
#pragma unroll
            for (int r = 0; r < 16; ++r) pr[r] = __builtin_exp2f(acc[r] - m_run);

            float* prow = prow_base + kv0 + sub * 32;
#pragma unroll
            for (int g = 0; g < 4; ++g) {
                f32x4 st = { pr[4*g+0] * rinv, pr[4*g+1] * rinv, pr[4*g+2] * rinv, pr[4*g+3] * rinv };
                *(f32x4*)(prow + g * 8 + hi * 4) = st;
            }

            unsigned u[8];
#pragma unroll
            for (int j = 0; j < 8; ++j)
                u[j] = (unsigned)f2bf(pr[2*j]) | ((unsigned)f2bf(pr[2*j+1]) << 16);

            unsigned s0 = __shfl_xor(u[0], 32), s1 = __shfl_xor(u[1], 32);
            unsigned s2 = __shfl_xor(u[2], 32), s3 = __shfl_xor(u[3], 32);
            unsigned s4 = __shfl_xor(u[4], 32), s5 = __shfl_xor(u[5], 32);
            unsigned s6 = __shfl_xor(u[6], 32), s7 = __shfl_xor(u[7], 32);
            PFrag pf0, pf1;
            pf0.w[0] = hi ? s2 : u[0];  pf0.w[1] = hi ? s3 : u[1];
            pf0.w[2] = hi ? u[2] : s0;  pf0.w[3] = hi ? u[3] : s1;
            pf1.w[0] = hi ? s6 : u[4];  pf1.w[1] = hi ? s7 : u[5];
            pf1.w[2] = hi ? u[6] : s4;  pf1.w[3] = hi ? u[7] : s5;

#pragma unroll
            for (int dt = 0; dt < 2; ++dt) {
                int drow = dt * 32 + lo5;
                int c0 = ((sub * 4) + 0 + hi) ^ (drow & 7);
                int c1 = ((sub * 4) + 2 + hi) ^ (drow & 7);
                bf16x8 vf0 = *(const bf16x8*)(Vt + drow * 64 + (c0 << 3));
                bf16x8 vf1 = *(const bf16x8*)(Vt + drow * 64 + (c1 << 3));
                f32x16& od = dt ? o1 : o0;
                od = __builtin_amdgcn_mfma_f32_32x32x16_bf16(vf0, pf0.v, od, 0, 0, 0);
                od = __builtin_amdgcn_mfma_f32_32x32x16_bf16(vf1, pf1.v, od, 0, 0, 0);
            }
        }
    }

    float* orow = Oh + (size_t)qg * DD;
#pragma unroll
    for (int dt = 0; dt < 2; ++dt) {
        const f32x16& od = dt ? o1 : o0;
#pragma unroll
        for (int g = 0; g < 4; ++g) {
            f32x4 st = { od[4*g+0] * rinv, od[4*g+1] * rinv, od[4*g+2] * rinv, od[4*g+3] * rinv };
            *(f32x4*)(orow + dt * 32 + g * 8 + hi * 4) = st;
        }
    }
}

extern "C" void kernel_launch(void* const* d_in, const int* in_sizes, int n_in,
                              void* d_out, int out_size, void* d_ws, size_t ws_size,
                              hipStream_t stream) {
    const float* Q = (const float*)d_in[0];
    const float* K = (const float*)d_in[1];
    const float* V = (const float*)d_in[2];
    float* O = (float*)d_out;
    float* P = O + (size_t)2 * 16 * SS * DD;

    const size_t HD = (size_t)32 * SS * DD;           // elems per tensor
    const size_t need = 2 * HD * sizeof(ushort_t);    // K bf16 + V^T bf16 ≈ 16.8 MB

    if (ws_size >= need) {
        ushort_t* Kbf  = (ushort_t*)d_ws;
        ushort_t* Vtbf = Kbf + HD;
        int n8 = (int)(HD / 8);
        hipLaunchKernelGGL(cvt_bf16, dim3(n8 / 256), dim3(256), 0, stream, K, Kbf, n8, 1.0f);
        hipLaunchKernelGGL(transposeV, dim3(1024), dim3(256), 0, stream, V, Vtbf);
        hipLaunchKernelGGL(attn_main4, dim3(1024), dim3(256), 0, stream, Q, Kbf, Vtbf, O, P);
    } else {
        hipLaunchKernelGGL(attn_fused, dim3(512), dim3(256), 0, stream, Q, K, V, O, P);
    }
}